// Round 9
// baseline (32659.799 us; speedup 1.0000x reference)
//
#include <hip/hip_runtime.h>
#include <math.h>

// ESN reservoir, persistent kernel, round 9.
// h_t = tanh(x_t Win^T + h_{t-1} W^T); out_t = h_t Wout^T + b
//
// r8 measured (VALUBusy 28.7%, step 8.56us): barrier ~1 + h-exchange ~3.5
// (2MB/step UC) + max(W-L2 3.7, VALU 2.5) + 0.4. Round 9 halves the W and
// VALU terms: W converted once to fp16 in ws (8MB, ws_size-guarded with
// fp32-W fallback path), h in fp16, inner loop = v_dot2_f32_f16 (fdot2:
// 2 MAC/inst, fp32 accumulate, no unpack). W chunk-0 prefetched into regs
// before the stage-wait so W latency hides under the UC exchange.
// Exchange/barrier/projection identical to r8:
//   block = 64 rows x 2 batches (rg=blk&31, g=blk>>5); 8KB h stage UC;
//   8 independent 32-block group barriers; rotating projection block.
// All spins bounded: worst case wrong answer, never a hang.

#define RDIM   2048
#define BATCH  16
#define TSTEPS 2048
#define NIN    3
#define NOUT   3
#define NBLK   256
#define NTHR   512

#define HB_U32    ((BATCH * RDIM) / 2)      // 16384 dwords (packed f16x2)
#define OFF_H0    0
#define OFF_H1    (HB_U32)
#define OFF_FLAGS (2 * HB_U32)              // 256 dwords: group g at [g*32..+31]
#define OFF_GO    (OFF_FLAGS + 256)         // 8 groups x 16-dword stride
#define OFF_WF16  (OFF_GO + 128)            // byte 132608 (16B aligned)
#define WF16_U32  (RDIM * RDIM / 2)         // 2M dwords = 8 MB
#define SPIN_MAX  (1L << 20)

#define CPOL_SC0_SC1 0x11                   // UC: read at coherence point

typedef _Float16 half2v __attribute__((ext_vector_type(2)));
union HU { unsigned u; half2v h; };

__device__ __forceinline__ void load_lds16(const void* g, void* l) {
    __builtin_amdgcn_global_load_lds(
        (const __attribute__((address_space(1))) void*)g,
        (__attribute__((address_space(3))) void*)l, 16, 0, CPOL_SC0_SC1);
}

__device__ __forceinline__ unsigned sysld(const unsigned* p) {
    return __hip_atomic_load(p, __ATOMIC_RELAXED, __HIP_MEMORY_SCOPE_SYSTEM);
}
__device__ __forceinline__ void sysst(unsigned* p, unsigned v) {
    __hip_atomic_store(p, v, __ATOMIC_RELAXED, __HIP_MEMORY_SCOPE_SYSTEM);
}

__device__ __forceinline__ float f16lo(unsigned u) { HU c; c.u = u; return (float)c.h.x; }
__device__ __forceinline__ float f16hi(unsigned u) { HU c; c.u = u; return (float)c.h.y; }
__device__ __forceinline__ unsigned packf16(float a, float b) {
    HU c; c.h.x = (_Float16)a; c.h.y = (_Float16)b; return c.u;
}
__device__ __forceinline__ float f16s(unsigned short s) {
    union { unsigned short u; _Float16 h; } c; c.u = s; return (float)c.h;
}

// 8-element f16 dot: wq . hq + c, fp32 accumulate
__device__ __forceinline__ float dot8(uint4 wq, uint4 hq, float c) {
#if __has_builtin(__builtin_amdgcn_fdot2)
    HU a, b;
    a.u = wq.x; b.u = hq.x; c = __builtin_amdgcn_fdot2(a.h, b.h, c, false);
    a.u = wq.y; b.u = hq.y; c = __builtin_amdgcn_fdot2(a.h, b.h, c, false);
    a.u = wq.z; b.u = hq.z; c = __builtin_amdgcn_fdot2(a.h, b.h, c, false);
    a.u = wq.w; b.u = hq.w; c = __builtin_amdgcn_fdot2(a.h, b.h, c, false);
#else
    c += f16lo(wq.x) * f16lo(hq.x) + f16hi(wq.x) * f16hi(hq.x);
    c += f16lo(wq.y) * f16lo(hq.y) + f16hi(wq.y) * f16hi(hq.y);
    c += f16lo(wq.z) * f16lo(hq.z) + f16hi(wq.z) * f16hi(hq.z);
    c += f16lo(wq.w) * f16lo(hq.w) + f16hi(wq.w) * f16hi(hq.w);
#endif
    return c;
}

extern "C" __global__ __launch_bounds__(256) void w_to_f16(
    const float* __restrict__ W, unsigned* __restrict__ Wf)
{
    const int i = blockIdx.x * 256 + threadIdx.x;    // over 2M output dwords
    float2 v = ((const float2*)W)[i];
    Wf[i] = packf16(v.x, v.y);
}

extern "C" __global__ void __launch_bounds__(NTHR, 1) esn_persist(
    const float* __restrict__ W,       // [R,R] fp32
    const float* __restrict__ Win,     // [R,3]
    const float* __restrict__ x,       // [B,T,3]
    const float* __restrict__ Wout,    // [3,R]
    const float* __restrict__ bout,    // [3]
    unsigned* hb0,                     // [B][R/2] packed f16x2
    unsigned* hb1,
    unsigned* flags,                   // [256]
    unsigned* go,                      // [8*16]
    const unsigned* __restrict__ Wf16, // [R][R/2] packed f16x2 (if use_f16w)
    int use_f16w,
    float* __restrict__ out)           // [B,T,3]
{
    __shared__ unsigned short hs[2 * RDIM];     // 8 KB: h for 2 batches
    __shared__ float red[8][544];               // transpose-reduce scratch
    __shared__ float hblk[64][2];               // block's 64 rows x 2 batches

    const int tid  = threadIdx.x;
    const int lane = tid & 63;
    const int w    = tid >> 6;                  // wave 0..7
    const int blk  = blockIdx.x;
    const int rg   = blk & 31;                  // row-group: rows rg*64..+64
    const int g    = blk >> 5;                  // batch-group: batches g*2..+2
    const int rbase = rg * 64 + w * 8;          // wave's 8 rows
    const int b0    = g * 2;                    // block's first batch

    const float4* W4 = (const float4*)W;
    const uint4*  WF = (const uint4*)Wf16;      // row r at WF[r*256 .. +256]

    for (int t = 0; t <= TSTEPS; ++t) {
        const unsigned* hprev = (t & 1) ? hb1 : hb0;
        unsigned*       hnext = (t & 1) ? hb0 : hb1;

        // ---- group barrier: wait for state version t ----
        if (t > 0) {
            const unsigned tgt = (unsigned)t;
            if (rg == 0) {
                if (w == 0) {
                    long spins = 0;             // sole poller of group flags
                    for (;;) {
                        unsigned vv = (lane < 32) ? sysld(&flags[g * 32 + lane]) : tgt;
                        if (__all((int)(vv >= tgt))) break;
                        __builtin_amdgcn_s_sleep(2);
                        if (++spins > SPIN_MAX) break;   // never hang
                    }
                    if (lane == 0) sysst(&go[g * 16], tgt);
                }
                __syncthreads();
            } else {
                if (tid == 0) {
                    long spins = 0;             // <=31 pollers on go[g]
                    while (sysld(&go[g * 16]) < tgt) {
                        __builtin_amdgcn_s_sleep(2);
                        if (++spins > SPIN_MAX) break;
                    }
                }
                __syncthreads();
            }
        }

        // ---- stage h[b0..b0+1][:] (8 KB) -> LDS: 512 granules, 1/thread ----
        {
            const int gran = w * 64 + lane;     // 16B granule 0..511
            load_lds16(hprev + (size_t)g * 2048 + (size_t)gran * 4,
                       hs + (size_t)(w * 64) * 8);
        }

        // ---- W chunk-0 register prefetch: overlaps the UC stage latency ----
        uint4 wq[8];
        if (use_f16w && t < TSTEPS) {
#pragma unroll
            for (int r = 0; r < 8; ++r)
                wq[r] = WF[(size_t)(rbase + r) * 256 + lane];
        }
        __syncthreads();   // staging complete (drains vmcnt)

        if (t < TSTEPS) {
            float acc[8][2];
#pragma unroll
            for (int r = 0; r < 8; ++r) { acc[r][0] = 0.f; acc[r][1] = 0.f; }

            const uint4* h16 = (const uint4*)hs;    // 256 granules per batch

            if (use_f16w) {
                // ---- fp16 W path: fdot2, reg double-buffered W ----
#pragma unroll
                for (int c = 0; c < 4; ++c) {
                    const int gr = c * 64 + lane;
                    uint4 q0 = h16[gr];
                    uint4 q1 = h16[256 + gr];
                    uint4 wn[8];
                    if (c < 3) {
#pragma unroll
                        for (int r = 0; r < 8; ++r)
                            wn[r] = WF[(size_t)(rbase + r) * 256 + (c + 1) * 64 + lane];
                    }
#pragma unroll
                    for (int r = 0; r < 8; ++r) {
                        acc[r][0] = dot8(wq[r], q0, acc[r][0]);
                        acc[r][1] = dot8(wq[r], q1, acc[r][1]);
                    }
                    if (c < 3) {
#pragma unroll
                        for (int r = 0; r < 8; ++r) wq[r] = wn[r];
                    }
                }
            } else {
                // ---- fallback: fp32 W, unpack f16 h (r8 structure) ----
#pragma unroll
                for (int c = 0; c < 4; ++c) {
                    const int gr = c * 64 + lane;
                    uint4 q0 = h16[gr];
                    uint4 q1 = h16[256 + gr];
                    float a0 = f16lo(q0.x), a1 = f16hi(q0.x);
                    float a2 = f16lo(q0.y), a3 = f16hi(q0.y);
                    float a4 = f16lo(q0.z), a5 = f16hi(q0.z);
                    float a6 = f16lo(q0.w), a7 = f16hi(q0.w);
                    float c0 = f16lo(q1.x), c1 = f16hi(q1.x);
                    float c2 = f16lo(q1.y), c3 = f16hi(q1.y);
                    float c4 = f16lo(q1.z), c5 = f16hi(q1.z);
                    float c6 = f16lo(q1.w), c7 = f16hi(q1.w);
#pragma unroll
                    for (int r = 0; r < 8; ++r) {
                        const float4* Wp = W4 + (size_t)(rbase + r) * (RDIM / 4) + gr * 2;
                        float4 w0 = Wp[0];
                        float4 w1 = Wp[1];
                        acc[r][0] += w0.x * a0 + w0.y * a1 + w0.z * a2 + w0.w * a3
                                   + w1.x * a4 + w1.y * a5 + w1.z * a6 + w1.w * a7;
                        acc[r][1] += w0.x * c0 + w0.y * c1 + w0.z * c2 + w0.w * c3
                                   + w1.x * c4 + w1.y * c5 + w1.z * c6 + w1.w * c7;
                    }
                }
            }

            // ---- reduce: fold 32, transpose, sum 32 partials ----
            float v[16];
#pragma unroll
            for (int i = 0; i < 16; ++i) {
                float a = acc[i >> 1][i & 1];
                v[i] = a + __shfl_xor(a, 32, 64);
            }
            if (lane < 32) {
#pragma unroll
                for (int i = 0; i < 16; ++i)
                    red[w][lane * 17 + ((i + lane) & 15)] = v[i];
            }
            __syncthreads();
            if (lane < 16) {
                float s = 0.f;
#pragma unroll
                for (int l = 0; l < 32; ++l)
                    s += red[w][l * 17 + ((lane + l) & 15)];
                const int r   = lane >> 1;          // 0..7
                const int b   = lane & 1;
                const int row = rbase + r;
                const int bg  = b0 + b;
                float pre = s;
#pragma unroll
                for (int c = 0; c < NIN; ++c)
                    pre += Win[row * NIN + c] * x[((size_t)bg * TSTEPS + t) * NIN + c];
                hblk[w * 8 + r][b] = tanhf(pre);
            }
            __syncthreads();   // hblk complete

            // ---- write h_new strips (UC): 64 packed dwords by wave 0 ----
            if (w == 0) {
                const int b = lane >> 5;            // 0..1
                const int j = lane & 31;            // dword within 64-row strip
                sysst(&hnext[(size_t)(b0 + b) * (RDIM / 2) + rg * 32 + j],
                      packf16(hblk[2 * j][b], hblk[2 * j + 1][b]));
                __builtin_amdgcn_s_waitcnt(0);      // strips visible first
            }
            __syncthreads();
            if (tid == 0) sysst(&flags[g * 32 + rg], (unsigned)(t + 1));
        }

        // ---- projection of H_t for this group's 2 batches (rotating) ----
        if (t > 0 && rg == ((t - 1) & 31)) {
            const int o = t - 1;
            if (w < 6) {
                const int b = w / NOUT;             // 0..1
                const int k = w % NOUT;             // 0..2
                float a = 0.f;
#pragma unroll
                for (int j = 0; j < 32; ++j) {
                    const int r = j * 64 + lane;
                    a += f16s(hs[b * RDIM + r]) * Wout[k * RDIM + r];
                }
#pragma unroll
                for (int off = 32; off >= 1; off >>= 1)
                    a += __shfl_xor(a, off, 64);
                if (lane == 0)
                    out[((size_t)(b0 + b) * TSTEPS + o) * NOUT + k] = a + bout[k];
            }
        }
    }
}

extern "C" void kernel_launch(void* const* d_in, const int* in_sizes, int n_in,
                              void* d_out, int out_size, void* d_ws, size_t ws_size,
                              hipStream_t stream) {
    const float* x    = (const float*)d_in[0];
    const float* Win  = (const float*)d_in[1];
    const float* W    = (const float*)d_in[2];
    const float* Wout = (const float*)d_in[3];
    const float* bout = (const float*)d_in[4];
    float* out = (float*)d_out;

    unsigned* wsu   = (unsigned*)d_ws;
    unsigned* hb0   = wsu + OFF_H0;
    unsigned* hb1   = wsu + OFF_H1;
    unsigned* flags = wsu + OFF_FLAGS;
    unsigned* go    = wsu + OFF_GO;
    unsigned* wf16  = wsu + OFF_WF16;

    // fp16-W path needs ~8.5 MB of ws; fall back to fp32 W if unavailable.
    int use_f16w = (ws_size >= (size_t)(OFF_WF16 + WF16_U32) * sizeof(unsigned));

    // zero h buffers + flags + go (~133 KB); Wf16 filled by prep kernel
    hipMemsetAsync(d_ws, 0, (size_t)OFF_WF16 * sizeof(unsigned), stream);
    if (use_f16w)
        w_to_f16<<<dim3(WF16_U32 / 256), dim3(256), 0, stream>>>(W, wf16);

    void* args[] = {(void*)&W, (void*)&Win, (void*)&x, (void*)&Wout, (void*)&bout,
                    (void*)&hb0, (void*)&hb1, (void*)&flags, (void*)&go,
                    (void*)&wf16, (void*)&use_f16w, (void*)&out};
    hipError_t e = hipLaunchCooperativeKernel((const void*)esn_persist,
                                              dim3(NBLK), dim3(NTHR),
                                              args, 0, stream);
    if (e != hipSuccess) {
        // Fallback: plain launch (256 blocks co-resident on 256 CUs; bounded
        // spins guarantee no hang regardless).
        esn_persist<<<dim3(NBLK), dim3(NTHR), 0, stream>>>(
            W, Win, x, Wout, bout, hb0, hb1, flags, go, wf16, use_f16w, out);
    }
}

// Round 10
// 20292.252 us; speedup vs baseline: 1.6095x; 1.6095x over previous
//
#include <hip/hip_runtime.h>
#include <math.h>

// ESN reservoir, persistent kernel, round 10.
// h_t = tanh(x_t Win^T + h_{t-1} W^T); out_t = h_t Wout^T + b
//
// r9 post-mortem: fp16 W in d_ws is NOT L2-resident (FETCH x10, dur 2x) ->
// W stays fp32 in d_in (proven 0.27 MB/step HBM). Keep f16 h (absmax 0.0039).
// r8 budget: step 8.56us = sync+exchange ~4.3 + max(W-L2 3.8, VALU 2.5) + 0.4.
// Round 10 overlaps exchange/sync with compute via k-chunk pipelining:
//  - k split into 4 chunks of 512; chunk c of h_t is produced exactly by
//    row-groups 8c..8c+7 -> consumer gates chunk c on those 8 flags only
//    (no all-32 barrier, no go round-trip).
//  - exchange = 1 dword/thread/chunk: UC reg load issued right after the
//    previous chunk barrier (latency hides under that chunk's compute),
//    then ds_write + __syncthreads (drains only an almost-elapsed load).
//  - compute/epilogue/projection structurally identical to r8 (fp32 W FMA,
//    swizzled transpose reduce, rotating projection block, f16 h pack).
//  - All spins bounded: worst case wrong answer, never a hang.

#define RDIM   2048
#define BATCH  16
#define TSTEPS 2048
#define NIN    3
#define NOUT   3
#define NBLK   256
#define NTHR   512

#define HB_U32    ((BATCH * RDIM) / 2)      // 16384 dwords (packed f16x2)
#define OFF_H0    0
#define OFF_H1    (HB_U32)
#define OFF_FLAGS (2 * HB_U32)              // 256 dwords: group g at [g*32..+31]
#define WS_USED   (OFF_FLAGS + 256)
#define SPIN_MAX  (1L << 20)

typedef _Float16 half2v __attribute__((ext_vector_type(2)));
union HU { unsigned u; half2v h; };

__device__ __forceinline__ unsigned sysld(const unsigned* p) {
    return __hip_atomic_load(p, __ATOMIC_RELAXED, __HIP_MEMORY_SCOPE_SYSTEM);
}
__device__ __forceinline__ void sysst(unsigned* p, unsigned v) {
    __hip_atomic_store(p, v, __ATOMIC_RELAXED, __HIP_MEMORY_SCOPE_SYSTEM);
}

__device__ __forceinline__ float f16lo(unsigned u) { HU c; c.u = u; return (float)c.h.x; }
__device__ __forceinline__ float f16hi(unsigned u) { HU c; c.u = u; return (float)c.h.y; }
__device__ __forceinline__ unsigned packf16(float a, float b) {
    HU c; c.h.x = (_Float16)a; c.h.y = (_Float16)b; return c.u;
}
__device__ __forceinline__ float f16s(unsigned short s) {
    union { unsigned short u; _Float16 h; } c; c.u = s; return (float)c.h;
}

extern "C" __global__ void __launch_bounds__(NTHR, 1) esn_persist(
    const float* __restrict__ W,       // [R,R] fp32 (d_in: L2-resident)
    const float* __restrict__ Win,     // [R,3]
    const float* __restrict__ x,       // [B,T,3]
    const float* __restrict__ Wout,    // [3,R]
    const float* __restrict__ bout,    // [3]
    unsigned* hb0,                     // [B][R/2] packed f16x2
    unsigned* hb1,
    unsigned* flags,                   // [256]
    float* __restrict__ out)           // [B,T,3]
{
    __shared__ unsigned hs_dw[2 * (RDIM / 2)];  // 8 KB: h for 2 batches
    __shared__ float red[8][544];               // transpose-reduce scratch
    __shared__ float hblk[64][2];               // block's 64 rows x 2 batches

    const int tid  = threadIdx.x;
    const int lane = tid & 63;
    const int w    = tid >> 6;                  // wave 0..7
    const int blk  = blockIdx.x;
    const int rg   = blk & 31;                  // row-group: rows rg*64..+64
    const int g    = blk >> 5;                  // batch-group: batches g*2..+2
    const int rbase = rg * 64 + w * 8;          // wave's 8 rows
    const int b0    = g * 2;                    // block's first batch
    const int bsel  = tid >> 8;                 // 0..1: which batch I stage
    const int idx   = tid & 255;                // dword within batch chunk

    const float4* W4 = (const float4*)W;

    for (int t = 0; t <= TSTEPS; ++t) {
        const unsigned* hprev = (t & 1) ? hb1 : hb0;
        unsigned*       hnext = (t & 1) ? hb0 : hb1;
        const unsigned  tgt   = (unsigned)t;    // h_t strips carry version t

        // ---- gate chunk 0: its 8 producers (rg 0..7) must be at >= t ----
        if (t > 0 && w == 0) {
            long spins = 0;
            for (;;) {
                unsigned vv = (lane < 8) ? sysld(&flags[g * 32 + lane]) : tgt;
                if (__all((int)(vv >= tgt))) break;
                __builtin_amdgcn_s_sleep(2);
                if (++spins > SPIN_MAX) break;   // never hang
            }
        }
        __syncthreads();
        // chunk 0 register load (UC, coalesced dwords)
        unsigned reg = sysld(&hprev[(size_t)(g * 2 + bsel) * 1024 + idx]);

        float acc[8][2];
#pragma unroll
        for (int r = 0; r < 8; ++r) { acc[r][0] = 0.f; acc[r][1] = 0.f; }

        // ---- pipelined chunks: write c to LDS, gate+load c+1, compute c ----
        for (int c = 0; c < 4; ++c) {
            hs_dw[bsel * 1024 + c * 256 + idx] = reg;
            if (c < 3 && t > 0 && w == 0) {
                long spins = 0;                  // producers rg 8(c+1)..+8
                for (;;) {
                    unsigned vv = (lane < 8)
                        ? sysld(&flags[g * 32 + (c + 1) * 8 + lane]) : tgt;
                    if (__all((int)(vv >= tgt))) break;
                    __builtin_amdgcn_s_sleep(2);
                    if (++spins > SPIN_MAX) break;
                }
            }
            __syncthreads();   // chunk c visible in LDS; c+1 confirmed ready
            if (c < 3)
                reg = sysld(&hprev[(size_t)(g * 2 + bsel) * 1024 + (c + 1) * 256 + idx]);

            if (t < TSTEPS) {
                const uint4* h4 = (const uint4*)hs_dw;
                uint4 q0 = h4[c * 64 + lane];           // batch b0
                uint4 q1 = h4[256 + c * 64 + lane];     // batch b0+1
                float a0 = f16lo(q0.x), a1 = f16hi(q0.x);
                float a2 = f16lo(q0.y), a3 = f16hi(q0.y);
                float a4 = f16lo(q0.z), a5 = f16hi(q0.z);
                float a6 = f16lo(q0.w), a7 = f16hi(q0.w);
                float c0 = f16lo(q1.x), c1 = f16hi(q1.x);
                float c2 = f16lo(q1.y), c3 = f16hi(q1.y);
                float c4 = f16lo(q1.z), c5 = f16hi(q1.z);
                float c6 = f16lo(q1.w), c7 = f16hi(q1.w);
#pragma unroll
                for (int r = 0; r < 8; ++r) {
                    const float4* Wp = W4 + (size_t)(rbase + r) * (RDIM / 4)
                                     + c * 128 + lane * 2;
                    float4 w0 = Wp[0];
                    float4 w1 = Wp[1];
                    acc[r][0] += w0.x * a0 + w0.y * a1 + w0.z * a2 + w0.w * a3
                               + w1.x * a4 + w1.y * a5 + w1.z * a6 + w1.w * a7;
                    acc[r][1] += w0.x * c0 + w0.y * c1 + w0.z * c2 + w0.w * c3
                               + w1.x * c4 + w1.y * c5 + w1.z * c6 + w1.w * c7;
                }
            }
        }

        if (t < TSTEPS) {
            // ---- reduce: fold 32, swizzled transpose, sum 32 partials ----
            float v[16];
#pragma unroll
            for (int i = 0; i < 16; ++i) {
                float a = acc[i >> 1][i & 1];
                v[i] = a + __shfl_xor(a, 32, 64);
            }
            if (lane < 32) {
#pragma unroll
                for (int i = 0; i < 16; ++i)
                    red[w][lane * 17 + ((i + lane) & 15)] = v[i];
            }
            __syncthreads();
            if (lane < 16) {
                float s = 0.f;
#pragma unroll
                for (int l = 0; l < 32; ++l)
                    s += red[w][l * 17 + ((lane + l) & 15)];
                const int r   = lane >> 1;          // 0..7
                const int b   = lane & 1;
                const int row = rbase + r;
                const int bg  = b0 + b;
                float pre = s;
#pragma unroll
                for (int c = 0; c < NIN; ++c)
                    pre += Win[row * NIN + c] * x[((size_t)bg * TSTEPS + t) * NIN + c];
                hblk[w * 8 + r][b] = tanhf(pre);
            }
            __syncthreads();   // hblk complete

            // ---- write h_new strips (UC) + version flag ----
            if (w == 0) {
                const int b = lane >> 5;            // 0..1
                const int j = lane & 31;            // dword within 64-row strip
                sysst(&hnext[(size_t)(b0 + b) * (RDIM / 2) + rg * 32 + j],
                      packf16(hblk[2 * j][b], hblk[2 * j + 1][b]));
                __builtin_amdgcn_s_waitcnt(0);      // strips visible first
                if (lane == 0) sysst(&flags[g * 32 + rg], (unsigned)(t + 1));
            }
        }

        // ---- projection of S_t (complete in hs) by rotating block ----
        if (t > 0 && rg == ((t - 1) & 31)) {
            const unsigned short* hsv = (const unsigned short*)hs_dw;
            const int o = t - 1;
            if (w < 6) {
                const int b = w / NOUT;             // 0..1
                const int k = w % NOUT;             // 0..2
                float a = 0.f;
#pragma unroll
                for (int j = 0; j < 32; ++j) {
                    const int r = j * 64 + lane;
                    a += f16s(hsv[b * RDIM + r]) * Wout[k * RDIM + r];
                }
#pragma unroll
                for (int off = 32; off >= 1; off >>= 1)
                    a += __shfl_xor(a, off, 64);
                if (lane == 0)
                    out[((size_t)(b0 + b) * TSTEPS + o) * NOUT + k] = a + bout[k];
            }
        }
    }
}

extern "C" void kernel_launch(void* const* d_in, const int* in_sizes, int n_in,
                              void* d_out, int out_size, void* d_ws, size_t ws_size,
                              hipStream_t stream) {
    const float* x    = (const float*)d_in[0];
    const float* Win  = (const float*)d_in[1];
    const float* W    = (const float*)d_in[2];
    const float* Wout = (const float*)d_in[3];
    const float* bout = (const float*)d_in[4];
    float* out = (float*)d_out;

    unsigned* wsu   = (unsigned*)d_ws;
    unsigned* hb0   = wsu + OFF_H0;
    unsigned* hb1   = wsu + OFF_H1;
    unsigned* flags = wsu + OFF_FLAGS;

    // zero h buffers + flags (~132 KB)
    hipMemsetAsync(d_ws, 0, (size_t)WS_USED * sizeof(unsigned), stream);

    void* args[] = {(void*)&W, (void*)&Win, (void*)&x, (void*)&Wout, (void*)&bout,
                    (void*)&hb0, (void*)&hb1, (void*)&flags, (void*)&out};
    hipError_t e = hipLaunchCooperativeKernel((const void*)esn_persist,
                                              dim3(NBLK), dim3(NTHR),
                                              args, 0, stream);
    if (e != hipSuccess) {
        // Fallback: plain launch (256 blocks co-resident on 256 CUs; bounded
        // spins guarantee no hang regardless).
        esn_persist<<<dim3(NBLK), dim3(NTHR), 0, stream>>>(
            W, Win, x, Wout, bout, hb0, hb1, flags, out);
    }
}